// Round 17
// baseline (77.873 us; speedup 1.0000x reference)
//
#include <hip/hip_runtime.h>
#include <cmath>

// Local contrast normalization — cross-tile software-pipelined version.
// x: [64,512,512,1] f32. 9x9 Gaussian (separable, center 4.5), SAME zero pad.
// Each block processes TWO vertically-adjacent 64x32 tiles (A, B) in 5
// staggered segments: {A.p1} {A.p2|B.p1} {A.p3|B.p2} {A.p4|B.p3} {B.p4}.
// Each interior segment mixes a global-load phase with an LDS/FMA phase ->
// ~2x per-wave ILP across independent streams; barriers/tile 4 -> 2.5.
// LDS 50.7 KB -> 3 blocks/CU (12 waves). Interior blocks run guard-free.

struct W9 { float w[9]; };

typedef float nf4 __attribute__((ext_vector_type(4)));  // nontemporal store

#define HW   512
#define HW4  128   // f4 per image row
#define TSY  32    // tile height (per sub-tile)
#define NH1  18    // h1/dd width in f4 (72 cols)
#define NH2  16    // h2/out width in f4 (64 cols)
#define RH1  48    // h1 rows
#define RDD  40    // dd/h2 rows

__device__ __forceinline__ float4 conv9(const float* X, const float* w) {
    float4 o = {0.f, 0.f, 0.f, 0.f};
#pragma unroll
    for (int j = 0; j < 9; ++j) {
        o.x = fmaf(w[j], X[j + 0], o.x);
        o.y = fmaf(w[j], X[j + 1], o.y);
        o.z = fmaf(w[j], X[j + 2], o.z);
        o.w = fmaf(w[j], X[j + 3], o.w);
    }
    return o;
}

// ---- phase task bodies ----

template <bool G>
__device__ __forceinline__ void p1_task(int o, const float* __restrict__ xb,
                                        int oxf, int oy, const float* w,
                                        float4* __restrict__ h1) {
    int r = o / NH1, m = o % NH1;
    int gy = oy - 8 + r;
    float4 o4 = {0.f, 0.f, 0.f, 0.f};
    if (!G || (gy >= 0 && gy < HW)) {
        const float4* row = reinterpret_cast<const float4*>(xb + (size_t)gy * HW);
        float X[12];
#pragma unroll
        for (int k = 0; k < 3; ++k) {
            int g4 = oxf - 2 + m + k;
            float4 v;
            if (G) v = (g4 >= 0 && g4 < HW4) ? row[g4] : float4{0.f, 0.f, 0.f, 0.f};
            else   v = row[g4];
            X[4 * k + 0] = v.x; X[4 * k + 1] = v.y;
            X[4 * k + 2] = v.z; X[4 * k + 3] = v.w;
        }
        o4 = conv9(X, w);
    }
    h1[o] = o4;
}

template <bool G>
__device__ __forceinline__ void p2_task(int t, const float* __restrict__ xb,
                                        int oxf, int oy, const float* w,
                                        const float4* __restrict__ h1,
                                        float4* __restrict__ dd) {
    int r = t / NH1, m = t % NH1;
    int gy = oy - 4 + r;
    int g4 = oxf - 1 + m;
    bool xin = !G || (gy >= 0 && gy < HW && g4 >= 0 && g4 < HW4);
    float4 xv = {0.f, 0.f, 0.f, 0.f};
    if (xin) xv = reinterpret_cast<const float4*>(xb + (size_t)gy * HW)[g4];
    float4 mean = {0.f, 0.f, 0.f, 0.f};
#pragma unroll
    for (int j = 0; j < 9; ++j) {
        const float4 h = h1[t + j * NH1];   // addr linear in tid
        mean.x = fmaf(w[j], h.x, mean.x);
        mean.y = fmaf(w[j], h.y, mean.y);
        mean.z = fmaf(w[j], h.z, mean.z);
        mean.w = fmaf(w[j], h.w, mean.w);
    }
    float4 d = {0.f, 0.f, 0.f, 0.f};
    if (xin) {
        d.x = xv.x - mean.x; d.y = xv.y - mean.y;
        d.z = xv.z - mean.z; d.w = xv.w - mean.w;
    }
    dd[t] = d;
}

__device__ __forceinline__ void p3_task(int o, const float* w,
                                        const float4* __restrict__ dd,
                                        float4* __restrict__ h2) {
    int r = o / NH2, n = o % NH2;
    float4 a = dd[r * NH1 + n];
    float4 b = dd[r * NH1 + n + 1];
    float4 c = dd[r * NH1 + n + 2];
    float X[12] = {a.x * a.x, a.y * a.y, a.z * a.z, a.w * a.w,
                   b.x * b.x, b.y * b.y, b.z * b.z, b.w * b.w,
                   c.x * c.x, c.y * c.y, c.z * c.z, c.w * c.w};
    h2[o] = conv9(X, w);   // o == r*16 + n, contiguous
}

__device__ __forceinline__ void p4_task(int t, float* __restrict__ ob,
                                        int oxf, int oy, const float* w,
                                        const float4* __restrict__ dd,
                                        const float4* __restrict__ h2) {
    int r = t >> 4, n = t & 15;
    float4 n2 = {0.f, 0.f, 0.f, 0.f};
#pragma unroll
    for (int j = 0; j < 9; ++j) {
        const float4 h = h2[t + j * NH2];   // addr linear in t
        n2.x = fmaf(w[j], h.x, n2.x);
        n2.y = fmaf(w[j], h.y, n2.y);
        n2.z = fmaf(w[j], h.z, n2.z);
        n2.w = fmaf(w[j], h.w, n2.w);
    }
    float4 dv = dd[(r + 4) * NH1 + n + 1];
    nf4 o;  // keep <=> sqrt(n2) > 0.5 <=> n2 > 0.25
    { float nr = rsqrtf(n2.x); o.x = (n2.x > 0.25f) ? dv.x * nr : dv.x; }
    { float nr = rsqrtf(n2.y); o.y = (n2.y > 0.25f) ? dv.y * nr : dv.y; }
    { float nr = rsqrtf(n2.z); o.z = (n2.z > 0.25f) ? dv.z * nr : dv.z; }
    { float nr = rsqrtf(n2.w); o.w = (n2.w > 0.25f) ? dv.w * nr : dv.w; }
    __builtin_nontemporal_store(o,
        reinterpret_cast<nf4*>(ob + (size_t)(oy + r) * HW) + oxf + n);
}

// sweep helpers (tasks counts: p1 864, p2 720, p3 640, p4 512)
#define SWEEP_P1(G, OY, H1)                                     \
    p1_task<G>(tid,       xb, oxf, (OY), w, (H1));              \
    p1_task<G>(tid + 256, xb, oxf, (OY), w, (H1));              \
    p1_task<G>(tid + 512, xb, oxf, (OY), w, (H1));              \
    if (tid < 96) p1_task<G>(tid + 768, xb, oxf, (OY), w, (H1));
#define SWEEP_P2(G, OY, H1, DD)                                 \
    p2_task<G>(tid,       xb, oxf, (OY), w, (H1), (DD));        \
    p2_task<G>(tid + 256, xb, oxf, (OY), w, (H1), (DD));        \
    if (tid < 208) p2_task<G>(tid + 512, xb, oxf, (OY), w, (H1), (DD));
#define SWEEP_P3(DD, H2)                                        \
    p3_task(tid,       w, (DD), (H2));                          \
    p3_task(tid + 256, w, (DD), (H2));                          \
    if (tid < 128) p3_task(tid + 512, w, (DD), (H2));
#define SWEEP_P4(OY, DD, H2)                                    \
    p4_task(tid,       ob, oxf, (OY), w, (DD), (H2));           \
    p4_task(tid + 256, ob, oxf, (OY), w, (DD), (H2));

template <bool G>
__device__ __forceinline__ void run2(const float* __restrict__ xb,
                                     float* __restrict__ ob,
                                     int oxf, int oyA, const float* w,
                                     float4* sm, int tid) {
    float4* h1A = sm;                    // [48][18] = 864
    float4* ddA = sm + 864;              // [40][18] = 720
    float4* h1B = sm + 1584;             // 864
    float4* ddB = sm + 2448;             // 720  (total 3168 f4 = 50,688 B)
    float4* h2A = h1A;                   // aliases (h1 dead after its p2)
    float4* h2B = h1B;
    const int oyB = oyA + TSY;

    // seg1: A.p1
    SWEEP_P1(G, oyA, h1A)
    __syncthreads();
    // seg2: B.p1 (global loads fly) | A.p2 (LDS + 1 global/task)
    SWEEP_P1(G, oyB, h1B)
    SWEEP_P2(G, oyA, h1A, ddA)
    __syncthreads();
    // seg3: B.p2 | A.p3   (h2A overwrites h1A — dead since seg2)
    SWEEP_P2(G, oyB, h1B, ddB)
    SWEEP_P3(ddA, h2A)
    __syncthreads();
    // seg4: A.p4 | B.p3   (h2B overwrites h1B — dead since seg3)
    SWEEP_P3(ddB, h2B)
    SWEEP_P4(oyA, ddA, h2A)
    __syncthreads();
    // seg5: B.p4
    SWEEP_P4(oyB, ddB, h2B)
}

__global__ __launch_bounds__(256, 3) void lcn_kernel(const float* __restrict__ x,
                                                     float* __restrict__ out,
                                                     W9 wts) {
    __shared__ float4 sm[3168];          // 50,688 B -> 3 blocks/CU

    const int tid = threadIdx.x;
    const int oxf = blockIdx.x * NH2;
    const int oyA = blockIdx.y * (2 * TSY);
    const float* xb = x + (size_t)blockIdx.z * HW * HW;
    float* ob = out + (size_t)blockIdx.z * HW * HW;

    float w[9];
#pragma unroll
    for (int i = 0; i < 9; ++i) w[i] = wts.w[i];

    // interior: x f4-range [oxf-2, oxf+19] needs bx in 1..6;
    // y-range [oyA-8, oyA+32+39] = [by*64-8, by*64+71] needs by in 1..6.
    const bool interior = (blockIdx.x > 0 && blockIdx.x < gridDim.x - 1 &&
                           blockIdx.y > 0 && blockIdx.y < gridDim.y - 1);
    if (interior) run2<false>(xb, ob, oxf, oyA, w, sm, tid);
    else          run2<true >(xb, ob, oxf, oyA, w, sm, tid);
}

static W9 make_w() {
    // reference: sigmah = 9/6, exponent divides by 2*sigmah = 3.0;
    // taps centered at 4.5 (asymmetric); separable: w1 = g1 / sum(g1).
    double g[9], s = 0.0;
    for (int i = 0; i < 9; ++i) {
        double off = (double)i - 4.5;
        g[i] = exp(-(off * off) / 3.0);
        s += g[i];
    }
    W9 r;
    for (int i = 0; i < 9; ++i) r.w[i] = (float)(g[i] / s);
    return r;
}

extern "C" void kernel_launch(void* const* d_in, const int* in_sizes, int n_in,
                              void* d_out, int out_size, void* d_ws, size_t ws_size,
                              hipStream_t stream) {
    const float* x = (const float*)d_in[0];
    float* out = (float*)d_out;
    W9 w = make_w();
    dim3 grid(HW / 64, HW / (2 * TSY), 64);  // 8 x 8 x 64
    lcn_kernel<<<grid, dim3(256), 0, stream>>>(x, out, w);
}

// Round 18
// 47.750 us; speedup vs baseline: 1.6308x; 1.6308x over previous
//
#include <hip/hip_runtime.h>
#include <cmath>

// Local contrast normalization, fused tile kernel (r15 base + r18 changes).
// x: [64,512,512,1] f32. 9x9 Gaussian (separable, center 4.5), SAME zero pad.
// Tile: 64 wide x 32 tall, 256 threads, 25.3 KB LDS (6 blocks/CU).
// r18: (1) dd-prefill — p1 stashes its middle x-load into dd[], so p2 is
// fully vmem-free (x re-read eliminated); (2) p1 batches all 3 sweeps'
// global loads into registers before computing (forces loads in flight).
// Interior blocks (66%) run guard-free (r15). All LDS phases task-linear
// or group-consecutive => conflict-free b128.

struct W9 { float w[9]; };

typedef float nf4 __attribute__((ext_vector_type(4)));  // nontemporal store

#define HW   512
#define HW4  128   // f4 per image row
#define TSY  32    // output tile height
#define NH1  18    // h1/dd width in f4 (72 cols: ox-4 .. ox+67)
#define NH2  16    // h2/out width in f4 (64 cols)
#define RH1  48    // h1 rows  (oy-8 .. oy+39)
#define RDD  40    // dd/h2 rows (oy-4 .. oy+35)

__device__ __forceinline__ float4 conv9v(const float4 v[3], const float* w) {
    const float X[12] = {v[0].x, v[0].y, v[0].z, v[0].w,
                         v[1].x, v[1].y, v[1].z, v[1].w,
                         v[2].x, v[2].y, v[2].z, v[2].w};
    float4 o = {0.f, 0.f, 0.f, 0.f};
#pragma unroll
    for (int j = 0; j < 9; ++j) {
        o.x = fmaf(w[j], X[j + 0], o.x);
        o.y = fmaf(w[j], X[j + 1], o.y);
        o.z = fmaf(w[j], X[j + 2], o.z);
        o.w = fmaf(w[j], X[j + 3], o.w);
    }
    return o;
}

// ---- p1: load 3 x-f4s for task o (rows oy-8+r, cols oxf-2+m..+2) ----
template <bool G>
__device__ __forceinline__ void p1_load(int o, const float* __restrict__ xb,
                                        int oxf, int oy, float4 v[3]) {
    int r = o / NH1, m = o % NH1;
    int gy = oy - 8 + r;
    const float4* row = reinterpret_cast<const float4*>(xb + (size_t)gy * HW);
    bool rowin = !G || ((unsigned)gy < (unsigned)HW);
#pragma unroll
    for (int k = 0; k < 3; ++k) {
        int g4 = oxf - 2 + m + k;
        if (G) v[k] = (rowin && g4 >= 0 && g4 < HW4)
                          ? row[g4] : float4{0.f, 0.f, 0.f, 0.f};
        else   v[k] = row[g4];            // interior: provably in-range
    }
}

// h1[o] = h-conv; stash middle x (col oxf-1+m) into dd for p2 (t = o-72).
__device__ __forceinline__ void p1_fin(int o, const float4 v[3], const float* w,
                                       float4* __restrict__ h1,
                                       float4* __restrict__ dd) {
    h1[o] = conv9v(v, w);
    if (o >= 4 * NH1 && o < 44 * NH1) dd[o - 4 * NH1] = v[1];
}

// ---- p2: mean = v-conv(h1); dd[t] = x(prefilled) - mean. NO vmem. ----
template <bool G>
__device__ __forceinline__ void p2_task(int t, int oxf, int oy, const float* w,
                                        const float4* __restrict__ h1,
                                        float4* __restrict__ dd) {
    float4 xv = dd[t];                    // prefilled x (linear addr)
    float4 mean = {0.f, 0.f, 0.f, 0.f};
#pragma unroll
    for (int j = 0; j < 9; ++j) {
        const float4 h = h1[t + j * NH1]; // addr linear in tid + imm offset
        mean.x = fmaf(w[j], h.x, mean.x);
        mean.y = fmaf(w[j], h.y, mean.y);
        mean.z = fmaf(w[j], h.z, mean.z);
        mean.w = fmaf(w[j], h.w, mean.w);
    }
    float4 d = {xv.x - mean.x, xv.y - mean.y, xv.z - mean.z, xv.w - mean.w};
    if (G) {
        int r = t / NH1, m = t % NH1;
        int gy = oy - 4 + r, g4 = oxf - 1 + m;
        bool xin = ((unsigned)gy < (unsigned)HW) && ((unsigned)g4 < (unsigned)HW4);
        if (!xin) d = float4{0.f, 0.f, 0.f, 0.f};
    }
    dd[t] = d;
}

// ---- p3: h2[o] = h-conv(dd^2), contiguous write ----
__device__ __forceinline__ void p3_task(int o, const float* w,
                                        const float4* __restrict__ dd,
                                        float4* __restrict__ h2) {
    int r = o / NH2, n = o % NH2;
    float4 a = dd[r * NH1 + n];
    float4 b = dd[r * NH1 + n + 1];
    float4 c = dd[r * NH1 + n + 2];
    const float4 s[3] = {
        {a.x * a.x, a.y * a.y, a.z * a.z, a.w * a.w},
        {b.x * b.x, b.y * b.y, b.z * b.z, b.w * b.w},
        {c.x * c.x, c.y * c.y, c.z * c.z, c.w * c.w}};
    h2[o] = conv9v(s, w);   // o == r*16 + n, contiguous
}

template <bool G>
__device__ __forceinline__ void run_tile(const float* __restrict__ xb,
                                         float* __restrict__ ob,
                                         int oxf, int oy, const float* w,
                                         float4* sm, int tid) {
    float4* h1 = sm;                 // [48][18]
    float4* dd = sm + RH1 * NH1;     // [40][18]
    float4* h2 = sm;                 // [40][16], aliases h1 (dead after p2)

    // ---- p1: 864 tasks; batch the 3 full sweeps' loads, then tail ----
    {
        float4 va[3], vb[3], vc[3];
        p1_load<G>(tid,       xb, oxf, oy, va);
        p1_load<G>(tid + 256, xb, oxf, oy, vb);
        p1_load<G>(tid + 512, xb, oxf, oy, vc);
        p1_fin(tid,       va, w, h1, dd);
        p1_fin(tid + 256, vb, w, h1, dd);
        p1_fin(tid + 512, vc, w, h1, dd);
        if (tid < 96) {
            float4 vd[3];
            p1_load<G>(tid + 768, xb, oxf, oy, vd);
            p1_fin(tid + 768, vd, w, h1, dd);
        }
    }
    __syncthreads();

    // ---- p2: 720 tasks, vmem-free ----
    p2_task<G>(tid,       oxf, oy, w, h1, dd);
    p2_task<G>(tid + 256, oxf, oy, w, h1, dd);
    if (tid < 208) p2_task<G>(tid + 512, oxf, oy, w, h1, dd);
    __syncthreads();

    // ---- p3: 640 tasks ----
    p3_task(tid,       w, dd, h2);
    p3_task(tid + 256, w, dd, h2);
    if (tid < 128) p3_task(tid + 512, w, dd, h2);
    __syncthreads();

    // ---- p4: n2 = v-conv(h2); out = keep ? dd/sqrt(n2) : dd ----
    // 512 outputs: n = tid%16 (group-consecutive), 16 row-groups of 2.
    {
        int n = tid % NH2, rg = tid / NH2;
        int r0 = rg * 2;
        float4 ring[9];
#pragma unroll
        for (int i = 0; i < 9; ++i) ring[i] = h2[(r0 + i) * NH2 + n];
#pragma unroll
        for (int k = 0; k < 2; ++k) {
            if (k) ring[(k + 8) % 9] = h2[(r0 + 8 + k) * NH2 + n];
            float4 n2 = {0.f, 0.f, 0.f, 0.f};
#pragma unroll
            for (int j = 0; j < 9; ++j) {
                const float4 h = ring[(k + j) % 9];
                n2.x = fmaf(w[j], h.x, n2.x);
                n2.y = fmaf(w[j], h.y, n2.y);
                n2.z = fmaf(w[j], h.z, n2.z);
                n2.w = fmaf(w[j], h.w, n2.w);
            }
            float4 dv = dd[(r0 + k + 4) * NH1 + n + 1];
            nf4 o;  // keep <=> sqrt(n2) > 0.5 <=> n2 > 0.25
            { float nr = rsqrtf(n2.x); o.x = (n2.x > 0.25f) ? dv.x * nr : dv.x; }
            { float nr = rsqrtf(n2.y); o.y = (n2.y > 0.25f) ? dv.y * nr : dv.y; }
            { float nr = rsqrtf(n2.z); o.z = (n2.z > 0.25f) ? dv.z * nr : dv.z; }
            { float nr = rsqrtf(n2.w); o.w = (n2.w > 0.25f) ? dv.w * nr : dv.w; }
            __builtin_nontemporal_store(o,
                reinterpret_cast<nf4*>(ob + (size_t)(oy + r0 + k) * HW) + oxf + n);
        }
    }
}

__global__ __launch_bounds__(256, 6) void lcn_kernel(const float* __restrict__ x,
                                                     float* __restrict__ out,
                                                     W9 wts) {
    __shared__ float4 sm[RH1 * NH1 + RDD * NH1];  // 25,344 B

    const int tid = threadIdx.x;
    const int oxf = blockIdx.x * NH2;
    const int oy  = blockIdx.y * TSY;
    const float* xb = x + (size_t)blockIdx.z * HW * HW;
    float* ob = out + (size_t)blockIdx.z * HW * HW;

    float w[9];
#pragma unroll
    for (int i = 0; i < 9; ++i) w[i] = wts.w[i];

    // interior: x f4-range [oxf-2, oxf+19] in-image for bx 1..6;
    // y-range [oy-8, oy+39] in-image for by 1..14.
    const bool interior = (blockIdx.x > 0 && blockIdx.x < gridDim.x - 1 &&
                           blockIdx.y > 0 && blockIdx.y < gridDim.y - 1);
    if (interior) run_tile<false>(xb, ob, oxf, oy, w, sm, tid);
    else          run_tile<true >(xb, ob, oxf, oy, w, sm, tid);
}

static W9 make_w() {
    // reference: sigmah = 9/6, exponent divides by 2*sigmah = 3.0;
    // taps centered at 4.5 (asymmetric); separable: w1 = g1 / sum(g1).
    double g[9], s = 0.0;
    for (int i = 0; i < 9; ++i) {
        double off = (double)i - 4.5;
        g[i] = exp(-(off * off) / 3.0);
        s += g[i];
    }
    W9 r;
    for (int i = 0; i < 9; ++i) r.w[i] = (float)(g[i] / s);
    return r;
}

extern "C" void kernel_launch(void* const* d_in, const int* in_sizes, int n_in,
                              void* d_out, int out_size, void* d_ws, size_t ws_size,
                              hipStream_t stream) {
    const float* x = (const float*)d_in[0];
    float* out = (float*)d_out;
    W9 w = make_w();
    dim3 grid(HW / 64, HW / TSY, 64);  // 8 x 16 x 64
    lcn_kernel<<<grid, dim3(256), 0, stream>>>(x, out, w);
}

// Round 19
// 47.594 us; speedup vs baseline: 1.6362x; 1.0033x over previous
//
#include <hip/hip_runtime.h>
#include <cmath>

// Local contrast normalization, fused tile kernel (r18 base + r19 p2-pairing).
// x: [64,512,512,1] f32. 9x9 Gaussian (separable, center 4.5), SAME zero pad.
// Tile: 64 wide x 32 tall, 256 threads, 25.3 KB LDS (6 blocks/CU).
// r18: dd-prefill (p2 vmem-free), p1 batched loads, guard-free interior.
// r19: p2 computes VERTICAL PAIRS (rows r,r+1 per thread): 10 h1 reads
// serve 2 outputs (was 9 each); halves p2 addressing. Conflict-free map:
// sweep1 m=tid&15 (16-lane groups -> consecutive f4s), rp=tid>>4.

struct W9 { float w[9]; };

typedef float nf4 __attribute__((ext_vector_type(4)));  // nontemporal store

#define HW   512
#define HW4  128   // f4 per image row
#define TSY  32    // output tile height
#define NH1  18    // h1/dd width in f4 (72 cols: ox-4 .. ox+67)
#define NH2  16    // h2/out width in f4 (64 cols)
#define RH1  48    // h1 rows  (oy-8 .. oy+39)
#define RDD  40    // dd/h2 rows (oy-4 .. oy+35)

__device__ __forceinline__ float4 conv9v(const float4 v[3], const float* w) {
    const float X[12] = {v[0].x, v[0].y, v[0].z, v[0].w,
                         v[1].x, v[1].y, v[1].z, v[1].w,
                         v[2].x, v[2].y, v[2].z, v[2].w};
    float4 o = {0.f, 0.f, 0.f, 0.f};
#pragma unroll
    for (int j = 0; j < 9; ++j) {
        o.x = fmaf(w[j], X[j + 0], o.x);
        o.y = fmaf(w[j], X[j + 1], o.y);
        o.z = fmaf(w[j], X[j + 2], o.z);
        o.w = fmaf(w[j], X[j + 3], o.w);
    }
    return o;
}

__device__ __forceinline__ float4 f4fma(float s, float4 a, float4 acc) {
    return float4{fmaf(s, a.x, acc.x), fmaf(s, a.y, acc.y),
                  fmaf(s, a.z, acc.z), fmaf(s, a.w, acc.w)};
}

// ---- p1: load 3 x-f4s for task o (row oy-8+r, cols oxf-2+m..+2) ----
template <bool G>
__device__ __forceinline__ void p1_load(int o, const float* __restrict__ xb,
                                        int oxf, int oy, float4 v[3]) {
    int r = o / NH1, m = o % NH1;
    int gy = oy - 8 + r;
    const float4* row = reinterpret_cast<const float4*>(xb + (size_t)gy * HW);
    bool rowin = !G || ((unsigned)gy < (unsigned)HW);
#pragma unroll
    for (int k = 0; k < 3; ++k) {
        int g4 = oxf - 2 + m + k;
        if (G) v[k] = (rowin && g4 >= 0 && g4 < HW4)
                          ? row[g4] : float4{0.f, 0.f, 0.f, 0.f};
        else   v[k] = row[g4];            // interior: provably in-range
    }
}

// h1[o] = h-conv; stash middle x (col oxf-1+m) into dd for p2 (t = o-72).
__device__ __forceinline__ void p1_fin(int o, const float4 v[3], const float* w,
                                       float4* __restrict__ h1,
                                       float4* __restrict__ dd) {
    h1[o] = conv9v(v, w);
    if (o >= 4 * NH1 && o < 44 * NH1) dd[o - 4 * NH1] = v[1];
}

// ---- p2 pair: dd rows (2rp, 2rp+1), col m. 10 h1 reads -> 2 outputs. ----
template <bool G>
__device__ __forceinline__ void p2_pair(int rp, int m, int oxf, int oy,
                                        const float* w,
                                        const float4* __restrict__ h1,
                                        float4* __restrict__ dd) {
    const int r = 2 * rp;
    const int t0 = r * NH1 + m;
    float4 xv0 = dd[t0];                  // prefilled x (read before overwrite)
    float4 xv1 = dd[t0 + NH1];
    float4 h[10];
#pragma unroll
    for (int j = 0; j < 10; ++j) h[j] = h1[t0 + j * NH1];
    float4 m0 = {0.f, 0.f, 0.f, 0.f}, m1 = {0.f, 0.f, 0.f, 0.f};
#pragma unroll
    for (int j = 0; j < 9; ++j) {
        m0 = f4fma(w[j], h[j], m0);
        m1 = f4fma(w[j], h[j + 1], m1);
    }
    float4 d0 = {xv0.x - m0.x, xv0.y - m0.y, xv0.z - m0.z, xv0.w - m0.w};
    float4 d1 = {xv1.x - m1.x, xv1.y - m1.y, xv1.z - m1.z, xv1.w - m1.w};
    if (G) {
        int g4 = oxf - 1 + m;
        bool cin = ((unsigned)g4 < (unsigned)HW4);
        int gy0 = oy - 4 + r;
        if (!(cin && (unsigned)gy0 < (unsigned)HW))
            d0 = float4{0.f, 0.f, 0.f, 0.f};
        if (!(cin && (unsigned)(gy0 + 1) < (unsigned)HW))
            d1 = float4{0.f, 0.f, 0.f, 0.f};
    }
    dd[t0] = d0;
    dd[t0 + NH1] = d1;
}

// ---- p3: h2[o] = h-conv(dd^2), contiguous write ----
__device__ __forceinline__ void p3_task(int o, const float* w,
                                        const float4* __restrict__ dd,
                                        float4* __restrict__ h2) {
    int r = o / NH2, n = o % NH2;
    float4 a = dd[r * NH1 + n];
    float4 b = dd[r * NH1 + n + 1];
    float4 c = dd[r * NH1 + n + 2];
    const float4 s[3] = {
        {a.x * a.x, a.y * a.y, a.z * a.z, a.w * a.w},
        {b.x * b.x, b.y * b.y, b.z * b.z, b.w * b.w},
        {c.x * c.x, c.y * c.y, c.z * c.z, c.w * c.w}};
    h2[o] = conv9v(s, w);   // o == r*16 + n, contiguous
}

template <bool G>
__device__ __forceinline__ void run_tile(const float* __restrict__ xb,
                                         float* __restrict__ ob,
                                         int oxf, int oy, const float* w,
                                         float4* sm, int tid) {
    float4* h1 = sm;                 // [48][18]
    float4* dd = sm + RH1 * NH1;     // [40][18]
    float4* h2 = sm;                 // [40][16], aliases h1 (dead after p2)

    // ---- p1: 864 tasks; batch the 3 full sweeps' loads, then tail ----
    {
        float4 va[3], vb[3], vc[3];
        p1_load<G>(tid,       xb, oxf, oy, va);
        p1_load<G>(tid + 256, xb, oxf, oy, vb);
        p1_load<G>(tid + 512, xb, oxf, oy, vc);
        p1_fin(tid,       va, w, h1, dd);
        p1_fin(tid + 256, vb, w, h1, dd);
        p1_fin(tid + 512, vc, w, h1, dd);
        if (tid < 96) {
            float4 vd[3];
            p1_load<G>(tid + 768, xb, oxf, oy, vd);
            p1_fin(tid + 768, vd, w, h1, dd);
        }
    }
    __syncthreads();

    // ---- p2: 360 vertical pairs (rows partitioned by pairs; no race) ----
    // sweep1: 256 = rp 0..15 x m 0..15 (group-consecutive, conflict-free)
    p2_pair<G>(tid >> 4, tid & 15, oxf, oy, w, h1, dd);
    // tail: rp 16..19 x m 0..15 (64) + m 16..17 x rp 0..19 (40)
    if (tid < 64) p2_pair<G>(16 + (tid >> 4), tid & 15, oxf, oy, w, h1, dd);
    else if (tid < 104) {
        int idx = tid - 64;
        p2_pair<G>(idx >> 1, 16 + (idx & 1), oxf, oy, w, h1, dd);
    }
    __syncthreads();

    // ---- p3: 640 tasks ----
    p3_task(tid,       w, dd, h2);
    p3_task(tid + 256, w, dd, h2);
    if (tid < 128) p3_task(tid + 512, w, dd, h2);
    __syncthreads();

    // ---- p4: n2 = v-conv(h2); out = keep ? dd/sqrt(n2) : dd ----
    // 512 outputs: n = tid%16 (group-consecutive), 16 row-groups of 2.
    {
        int n = tid % NH2, rg = tid / NH2;
        int r0 = rg * 2;
        float4 ring[9];
#pragma unroll
        for (int i = 0; i < 9; ++i) ring[i] = h2[(r0 + i) * NH2 + n];
#pragma unroll
        for (int k = 0; k < 2; ++k) {
            if (k) ring[(k + 8) % 9] = h2[(r0 + 8 + k) * NH2 + n];
            float4 n2 = {0.f, 0.f, 0.f, 0.f};
#pragma unroll
            for (int j = 0; j < 9; ++j) {
                const float4 h = ring[(k + j) % 9];
                n2.x = fmaf(w[j], h.x, n2.x);
                n2.y = fmaf(w[j], h.y, n2.y);
                n2.z = fmaf(w[j], h.z, n2.z);
                n2.w = fmaf(w[j], h.w, n2.w);
            }
            float4 dv = dd[(r0 + k + 4) * NH1 + n + 1];
            nf4 o;  // keep <=> sqrt(n2) > 0.5 <=> n2 > 0.25
            { float nr = rsqrtf(n2.x); o.x = (n2.x > 0.25f) ? dv.x * nr : dv.x; }
            { float nr = rsqrtf(n2.y); o.y = (n2.y > 0.25f) ? dv.y * nr : dv.y; }
            { float nr = rsqrtf(n2.z); o.z = (n2.z > 0.25f) ? dv.z * nr : dv.z; }
            { float nr = rsqrtf(n2.w); o.w = (n2.w > 0.25f) ? dv.w * nr : dv.w; }
            __builtin_nontemporal_store(o,
                reinterpret_cast<nf4*>(ob + (size_t)(oy + r0 + k) * HW) + oxf + n);
        }
    }
}

__global__ __launch_bounds__(256, 6) void lcn_kernel(const float* __restrict__ x,
                                                     float* __restrict__ out,
                                                     W9 wts) {
    __shared__ float4 sm[RH1 * NH1 + RDD * NH1];  // 25,344 B

    const int tid = threadIdx.x;
    const int oxf = blockIdx.x * NH2;
    const int oy  = blockIdx.y * TSY;
    const float* xb = x + (size_t)blockIdx.z * HW * HW;
    float* ob = out + (size_t)blockIdx.z * HW * HW;

    float w[9];
#pragma unroll
    for (int i = 0; i < 9; ++i) w[i] = wts.w[i];

    // interior: x f4-range [oxf-2, oxf+19] in-image for bx 1..6;
    // y-range [oy-8, oy+39] in-image for by 1..14.
    const bool interior = (blockIdx.x > 0 && blockIdx.x < gridDim.x - 1 &&
                           blockIdx.y > 0 && blockIdx.y < gridDim.y - 1);
    if (interior) run_tile<false>(xb, ob, oxf, oy, w, sm, tid);
    else          run_tile<true >(xb, ob, oxf, oy, w, sm, tid);
}

static W9 make_w() {
    // reference: sigmah = 9/6, exponent divides by 2*sigmah = 3.0;
    // taps centered at 4.5 (asymmetric); separable: w1 = g1 / sum(g1).
    double g[9], s = 0.0;
    for (int i = 0; i < 9; ++i) {
        double off = (double)i - 4.5;
        g[i] = exp(-(off * off) / 3.0);
        s += g[i];
    }
    W9 r;
    for (int i = 0; i < 9; ++i) r.w[i] = (float)(g[i] / s);
    return r;
}

extern "C" void kernel_launch(void* const* d_in, const int* in_sizes, int n_in,
                              void* d_out, int out_size, void* d_ws, size_t ws_size,
                              hipStream_t stream) {
    const float* x = (const float*)d_in[0];
    float* out = (float*)d_out;
    W9 w = make_w();
    dim3 grid(HW / 64, HW / TSY, 64);  // 8 x 16 x 64
    lcn_kernel<<<grid, dim3(256), 0, stream>>>(x, out, w);
}

// Round 20
// 44.189 us; speedup vs baseline: 1.7623x; 1.0771x over previous
//
#include <hip/hip_runtime.h>
#include <cmath>

// Local contrast normalization, fused tile kernel (r19 base + r20 packed f32).
// x: [64,512,512,1] f32. 9x9 Gaussian (separable, center 4.5), SAME zero pad.
// Tile: 64 wide x 32 tall, 256 threads, 25.3 KB LDS (6 blocks/CU).
// r18: dd-prefill (p2 vmem-free). r19: p2 vertical pairs.
// r20: packed fp32 (v_pk_fma_f32 via __builtin_elementwise_fma on
// ext_vector float2): vertical convs pack .xy/.zw of each tap (aligned
// pairs), horizontal convs pack via pre-shifted pairs, squares pack.
// Same op order as scalar => bitwise-identical output.

struct W9 { float w[9]; };

typedef float nf4 __attribute__((ext_vector_type(4)));  // nontemporal store
typedef float f2  __attribute__((ext_vector_type(2)));  // packed math

__device__ __forceinline__ f2 ffma2(f2 a, f2 b, f2 c) {
    return __builtin_elementwise_fma(a, b, c);
}

#define HW   512
#define HW4  128   // f4 per image row
#define TSY  32    // output tile height
#define NH1  18    // h1/dd width in f4 (72 cols: ox-4 .. ox+67)
#define NH2  16    // h2/out width in f4 (64 cols)
#define RH1  48    // h1 rows  (oy-8 .. oy+39)
#define RDD  40    // dd/h2 rows (oy-4 .. oy+35)

// horizontal 9-tap on 12 floats -> 4 outputs, packed:
// o.xy taps pairs P[j] = {X[j],X[j+1]}, o.zw taps P[j+2].
__device__ __forceinline__ float4 conv9h(const float X[12], const float* w) {
    f2 P[11];
#pragma unroll
    for (int k = 0; k < 11; ++k) P[k] = f2{X[k], X[k + 1]};
    f2 lo = {0.f, 0.f}, hi = {0.f, 0.f};
#pragma unroll
    for (int j = 0; j < 9; ++j) {
        const f2 wj = {w[j], w[j]};
        lo = ffma2(wj, P[j], lo);
        hi = ffma2(wj, P[j + 2], hi);
    }
    return float4{lo.x, lo.y, hi.x, hi.y};
}

// ---- p1: load 3 x-f4s for task o (row oy-8+r, cols oxf-2+m..+2) ----
template <bool G>
__device__ __forceinline__ void p1_load(int o, const float* __restrict__ xb,
                                        int oxf, int oy, float4 v[3]) {
    int r = o / NH1, m = o % NH1;
    int gy = oy - 8 + r;
    const float4* row = reinterpret_cast<const float4*>(xb + (size_t)gy * HW);
    bool rowin = !G || ((unsigned)gy < (unsigned)HW);
#pragma unroll
    for (int k = 0; k < 3; ++k) {
        int g4 = oxf - 2 + m + k;
        if (G) v[k] = (rowin && g4 >= 0 && g4 < HW4)
                          ? row[g4] : float4{0.f, 0.f, 0.f, 0.f};
        else   v[k] = row[g4];            // interior: provably in-range
    }
}

// h1[o] = h-conv; stash middle x (col oxf-1+m) into dd for p2 (t = o-72).
__device__ __forceinline__ void p1_fin(int o, const float4 v[3], const float* w,
                                       float4* __restrict__ h1,
                                       float4* __restrict__ dd) {
    const float X[12] = {v[0].x, v[0].y, v[0].z, v[0].w,
                         v[1].x, v[1].y, v[1].z, v[1].w,
                         v[2].x, v[2].y, v[2].z, v[2].w};
    h1[o] = conv9h(X, w);
    if (o >= 4 * NH1 && o < 44 * NH1) dd[o - 4 * NH1] = v[1];
}

// ---- p2 pair: dd rows (2rp, 2rp+1), col m. Packed vertical conv. ----
template <bool G>
__device__ __forceinline__ void p2_pair(int rp, int m, int oxf, int oy,
                                        const float* w,
                                        const float4* __restrict__ h1,
                                        float4* __restrict__ dd) {
    const int r = 2 * rp;
    const int t0 = r * NH1 + m;
    float4 xv0 = dd[t0];                  // prefilled x (read before overwrite)
    float4 xv1 = dd[t0 + NH1];
    f2 hl[10], hh[10];
#pragma unroll
    for (int j = 0; j < 10; ++j) {
        float4 h = h1[t0 + j * NH1];
        hl[j] = f2{h.x, h.y};
        hh[j] = f2{h.z, h.w};
    }
    f2 m0l = {0.f, 0.f}, m0h = {0.f, 0.f}, m1l = {0.f, 0.f}, m1h = {0.f, 0.f};
#pragma unroll
    for (int j = 0; j < 9; ++j) {
        const f2 wj = {w[j], w[j]};
        m0l = ffma2(wj, hl[j], m0l);
        m0h = ffma2(wj, hh[j], m0h);
        m1l = ffma2(wj, hl[j + 1], m1l);
        m1h = ffma2(wj, hh[j + 1], m1h);
    }
    float4 d0 = {xv0.x - m0l.x, xv0.y - m0l.y, xv0.z - m0h.x, xv0.w - m0h.y};
    float4 d1 = {xv1.x - m1l.x, xv1.y - m1l.y, xv1.z - m1h.x, xv1.w - m1h.y};
    if (G) {
        int g4 = oxf - 1 + m;
        bool cin = ((unsigned)g4 < (unsigned)HW4);
        int gy0 = oy - 4 + r;
        if (!(cin && (unsigned)gy0 < (unsigned)HW))
            d0 = float4{0.f, 0.f, 0.f, 0.f};
        if (!(cin && (unsigned)(gy0 + 1) < (unsigned)HW))
            d1 = float4{0.f, 0.f, 0.f, 0.f};
    }
    dd[t0] = d0;
    dd[t0 + NH1] = d1;
}

// ---- p3: h2[o] = h-conv(dd^2); squares packed, conv packed ----
__device__ __forceinline__ void p3_task(int o, const float* w,
                                        const float4* __restrict__ dd,
                                        float4* __restrict__ h2) {
    int r = o / NH2, n = o % NH2;
    float4 a = dd[r * NH1 + n];
    float4 b = dd[r * NH1 + n + 1];
    float4 c = dd[r * NH1 + n + 2];
    f2 s0 = f2{a.x, a.y} * f2{a.x, a.y};
    f2 s1 = f2{a.z, a.w} * f2{a.z, a.w};
    f2 s2 = f2{b.x, b.y} * f2{b.x, b.y};
    f2 s3 = f2{b.z, b.w} * f2{b.z, b.w};
    f2 s4 = f2{c.x, c.y} * f2{c.x, c.y};
    f2 s5 = f2{c.z, c.w} * f2{c.z, c.w};
    const float X[12] = {s0.x, s0.y, s1.x, s1.y, s2.x, s2.y,
                         s3.x, s3.y, s4.x, s4.y, s5.x, s5.y};
    h2[o] = conv9h(X, w);   // o == r*16 + n, contiguous
}

template <bool G>
__device__ __forceinline__ void run_tile(const float* __restrict__ xb,
                                         float* __restrict__ ob,
                                         int oxf, int oy, const float* w,
                                         float4* sm, int tid) {
    float4* h1 = sm;                 // [48][18]
    float4* dd = sm + RH1 * NH1;     // [40][18]
    float4* h2 = sm;                 // [40][16], aliases h1 (dead after p2)

    // ---- p1: 864 tasks; batch the 3 full sweeps' loads, then tail ----
    {
        float4 va[3], vb[3], vc[3];
        p1_load<G>(tid,       xb, oxf, oy, va);
        p1_load<G>(tid + 256, xb, oxf, oy, vb);
        p1_load<G>(tid + 512, xb, oxf, oy, vc);
        p1_fin(tid,       va, w, h1, dd);
        p1_fin(tid + 256, vb, w, h1, dd);
        p1_fin(tid + 512, vc, w, h1, dd);
        if (tid < 96) {
            float4 vd[3];
            p1_load<G>(tid + 768, xb, oxf, oy, vd);
            p1_fin(tid + 768, vd, w, h1, dd);
        }
    }
    __syncthreads();

    // ---- p2: 360 vertical pairs ----
    p2_pair<G>(tid >> 4, tid & 15, oxf, oy, w, h1, dd);
    if (tid < 64) p2_pair<G>(16 + (tid >> 4), tid & 15, oxf, oy, w, h1, dd);
    else if (tid < 104) {
        int idx = tid - 64;
        p2_pair<G>(idx >> 1, 16 + (idx & 1), oxf, oy, w, h1, dd);
    }
    __syncthreads();

    // ---- p3: 640 tasks ----
    p3_task(tid,       w, dd, h2);
    p3_task(tid + 256, w, dd, h2);
    if (tid < 128) p3_task(tid + 512, w, dd, h2);
    __syncthreads();

    // ---- p4: n2 = v-conv(h2) packed; out = keep ? dd*rsqrt(n2) : dd ----
    // 512 outputs: n = tid%16 (group-consecutive), 16 row-groups of 2.
    {
        int n = tid % NH2, rg = tid / NH2;
        int r0 = rg * 2;
        f2 rl[10], rh[10];
#pragma unroll
        for (int i = 0; i < 10; ++i) {
            float4 h = h2[(r0 + i) * NH2 + n];
            rl[i] = f2{h.x, h.y};
            rh[i] = f2{h.z, h.w};
        }
#pragma unroll
        for (int k = 0; k < 2; ++k) {
            f2 nl = {0.f, 0.f}, nh = {0.f, 0.f};
#pragma unroll
            for (int j = 0; j < 9; ++j) {
                const f2 wj = {w[j], w[j]};
                nl = ffma2(wj, rl[k + j], nl);
                nh = ffma2(wj, rh[k + j], nh);
            }
            float4 dv = dd[(r0 + k + 4) * NH1 + n + 1];
            nf4 o;  // keep <=> sqrt(n2) > 0.5 <=> n2 > 0.25
            { float nr = rsqrtf(nl.x); o.x = (nl.x > 0.25f) ? dv.x * nr : dv.x; }
            { float nr = rsqrtf(nl.y); o.y = (nl.y > 0.25f) ? dv.y * nr : dv.y; }
            { float nr = rsqrtf(nh.x); o.z = (nh.x > 0.25f) ? dv.z * nr : dv.z; }
            { float nr = rsqrtf(nh.y); o.w = (nh.y > 0.25f) ? dv.w * nr : dv.w; }
            __builtin_nontemporal_store(o,
                reinterpret_cast<nf4*>(ob + (size_t)(oy + r0 + k) * HW) + oxf + n);
        }
    }
}

__global__ __launch_bounds__(256, 6) void lcn_kernel(const float* __restrict__ x,
                                                     float* __restrict__ out,
                                                     W9 wts) {
    __shared__ float4 sm[RH1 * NH1 + RDD * NH1];  // 25,344 B

    const int tid = threadIdx.x;
    const int oxf = blockIdx.x * NH2;
    const int oy  = blockIdx.y * TSY;
    const float* xb = x + (size_t)blockIdx.z * HW * HW;
    float* ob = out + (size_t)blockIdx.z * HW * HW;

    float w[9];
#pragma unroll
    for (int i = 0; i < 9; ++i) w[i] = wts.w[i];

    // interior: x f4-range [oxf-2, oxf+19] in-image for bx 1..6;
    // y-range [oy-8, oy+39] in-image for by 1..14.
    const bool interior = (blockIdx.x > 0 && blockIdx.x < gridDim.x - 1 &&
                           blockIdx.y > 0 && blockIdx.y < gridDim.y - 1);
    if (interior) run_tile<false>(xb, ob, oxf, oy, w, sm, tid);
    else          run_tile<true >(xb, ob, oxf, oy, w, sm, tid);
}

static W9 make_w() {
    // reference: sigmah = 9/6, exponent divides by 2*sigmah = 3.0;
    // taps centered at 4.5 (asymmetric); separable: w1 = g1 / sum(g1).
    double g[9], s = 0.0;
    for (int i = 0; i < 9; ++i) {
        double off = (double)i - 4.5;
        g[i] = exp(-(off * off) / 3.0);
        s += g[i];
    }
    W9 r;
    for (int i = 0; i < 9; ++i) r.w[i] = (float)(g[i] / s);
    return r;
}

extern "C" void kernel_launch(void* const* d_in, const int* in_sizes, int n_in,
                              void* d_out, int out_size, void* d_ws, size_t ws_size,
                              hipStream_t stream) {
    const float* x = (const float*)d_in[0];
    float* out = (float*)d_out;
    W9 w = make_w();
    dim3 grid(HW / 64, HW / TSY, 64);  // 8 x 16 x 64
    lcn_kernel<<<grid, dim3(256), 0, stream>>>(x, out, w);
}